// Round 5
// baseline (9815.807 us; speedup 1.0000x reference)
//
#include <hip/hip_runtime.h>
#include <cstdint>
#include <cstddef>

// ---------------------------------------------------------------------------
// RLSTM: B=32, T=1024, F=256, H=256.
// Identities: a_rec = a_cur[idx]; gate chunk 4 unused (o_t = i_t); x@W is
// recurrence-free (phase A). Phase B: 64 persistent WGs, each owns 4 h-cols
// (12 gate cols). R5 (= R4 fixed): R3 profile showed each __hip_atomic_load
// is a serialized ~0.35us MALL round trip (16/thread = 5.6us of the 7.8us
// step). Fix: inline-asm batched gather -- 8x global_load_dwordx4 sc0 sc1
// with 64-bit VGPR-pair addresses ("off" form; the saddr form miscompiled:
// LLVM put the "s" pointer in VGPRs) + ONE s_waitcnt; asm publish store.
// h@U remapped to 2jc x 2b register blocking with LDS broadcasts.
// Accumulation order per output unchanged -> absmax 0.0.
// ---------------------------------------------------------------------------

#define T_STEPS 1024
#define BSZ 32
#define FDIM 256
#define HDIM 256
#define G3W 384          // per-WG gate cols x batch (12*32) flat row
#define KWG 64           // phase-B workgroups (co-resident on 256 CUs)
#define HS 4             // h-cols per WG
#define JC 12            // gate cols per WG (3 chunks x HS)
#define HPAD 260         // LDS row pad
#define OMEGA 32
#define HSLICE 8192      // floats per hbank step slice (32*256)

static const size_t AXC_BYTES = (size_t)KWG * T_STEPS * G3W * sizeof(float);      // 96 MiB
static const size_t HB_BYTES  = (size_t)(T_STEPS + 1) * HSLICE * sizeof(float);   // 32 MiB
static const size_t GX_BYTES  = (size_t)T_STEPS * sizeof(double);

// ------------------------------ Phase A ------------------------------------
__global__ __launch_bounds__(256) void phaseA(const float* __restrict__ x,
                                              const float* __restrict__ W,
                                              const float* __restrict__ W_r,
                                              const float* __restrict__ P_r,
                                              float* __restrict__ AXc,
                                              double* __restrict__ gx) {
  const int t = blockIdx.x;
  const int tid = threadIdx.x;
  __shared__ __align__(16) float xs[BSZ][HPAD];
  __shared__ double sred[BSZ];

  for (int i = tid; i < BSZ * FDIM / 4; i += 256) {
    const int b = (i * 4) >> 8;
    const int k = (i * 4) & 255;
    *(float4*)&xs[b][k] = *(const float4*)&x[((size_t)b * T_STEPS + t) * FDIM + k];
  }
  __syncthreads();

  for (int pass = 0; pass < 3; ++pass) {
    const int j = pass * 256 + tid;           // gate col in [0,768)
    float acc[BSZ];
#pragma unroll
    for (int b = 0; b < BSZ; ++b) acc[b] = 0.f;
    for (int k0 = 0; k0 < FDIM; k0 += 4) {
      const float w0 = W[(size_t)(k0 + 0) * 1024 + j];
      const float w1 = W[(size_t)(k0 + 1) * 1024 + j];
      const float w2 = W[(size_t)(k0 + 2) * 1024 + j];
      const float w3 = W[(size_t)(k0 + 3) * 1024 + j];
#pragma unroll
      for (int b = 0; b < BSZ; ++b) {
        const float4 xv = *(const float4*)&xs[b][k0];  // LDS broadcast
        acc[b] = fmaf(xv.x, w0, acc[b]);
        acc[b] = fmaf(xv.y, w1, acc[b]);
        acc[b] = fmaf(xv.z, w2, acc[b]);
        acc[b] = fmaf(xv.w, w3, acc[b]);
      }
    }
    // AXc[wg][t][b*12 + slot], wg = (j%256)/4, slot = (j/256)*4 + j%4
    const int wgj = (j >> 2) & 63;
    const int slot = ((j >> 8) << 2) | (j & 3);
    float* dst = AXc + ((size_t)wgj * T_STEPS + t) * G3W + slot;
    for (int b = 0; b < BSZ; ++b) dst[b * 12] = acc[b];
  }

  if (tid < BSZ) {
    double s = 0.0;
    for (int k = 0; k < FDIM; k += 4) {
      const float4 xv = *(const float4*)&xs[tid][k];
      const float4 wv = *(const float4*)&W_r[k];
      s = fma((double)xv.x, (double)wv.x, s);
      s = fma((double)xv.y, (double)wv.y, s);
      s = fma((double)xv.z, (double)wv.z, s);
      s = fma((double)xv.w, (double)wv.w, s);
    }
    sred[tid] = s;
  }
  __syncthreads();
  if (tid == 0) {
    double g = 0.0;
    for (int b = 0; b < BSZ; ++b) g = fma((double)P_r[b], sred[b], g);
    gx[t] = g;
  }
}

// ------------------------------ Phase B ------------------------------------
__global__ __launch_bounds__(256) void phaseB(const float* __restrict__ U,
                                              const float* __restrict__ P,
                                              const float* __restrict__ B_bias,
                                              const float* __restrict__ P_r,
                                              const float* __restrict__ U_r,
                                              float* __restrict__ AXc,
                                              float* __restrict__ hbank,
                                              const double* __restrict__ gx,
                                              unsigned int* __restrict__ flags) {
  const int wg = blockIdx.x;
  const int tid = threadIdx.x;
  const int lane = tid & 63;

  __shared__ __align__(16) float ULt[JC][HPAD];   // U cols for this WG, k-major
  __shared__ __align__(16) float hL[BSZ][HPAD];   // h_{t-1}, full
  __shared__ __align__(16) float PL[BSZ][64];
  __shared__ __align__(16) float acs[JC][36];     // a_cur slice [jc][b]
  __shared__ __align__(16) float ars[JC][36];     // a_rec slice
  __shared__ __align__(16) float hpub[BSZ * HS];  // our h slice [b*4+c]
  __shared__ __align__(16) float UrL[FDIM];
  __shared__ float PrL[BSZ];
  __shared__ float biasL[JC];

  for (int i = tid; i < JC * HDIM; i += 256) {
    const int jc = i >> 8, k = i & 255;
    const int col = (jc >> 2) * HDIM + wg * HS + (jc & 3);
    ULt[jc][k] = U[(size_t)k * 1024 + col];
  }
  for (int i = tid; i < BSZ * 64; i += 256) PL[i >> 6][i & 63] = P[i];
  if (tid < FDIM) UrL[tid] = U_r[tid];
  if (tid < BSZ) PrL[tid] = P_r[tid];
  if (tid < JC) biasL[tid] = B_bias[(tid >> 2) * HDIM + wg * HS + (tid & 3)];

  // h@U mapping: threads 64..159 (96 active), 2jc x 2b register block.
  const int hs = tid - 64;
  const bool hAct = (tid >= 64) && (tid < 160);
  const int jp = (hs >> 4) % 6;            // [0,6)
  const int bp = hs & 15;                  // [0,16)
  const int jc0 = 2 * jp, jc1 = 2 * jp + 1;
  const int f00 = bp * 12 + jc0;           // flat (b,jc) for b=bp
  const int f10 = (bp + 16) * 12 + jc0;    // for b=bp+16

  const int ob = tid >> 2, ohc = tid & 3;  // owner mapping (tid<128)
  // gather scatter mapping: thread holds bytes [tid*128, +128)
  const int gbase = (tid & 3) * 8;         // first b row
  const int gcol = (tid >> 2) * 4;         // col base (wg2*4)

  float* __restrict__ AXwg = AXc + (size_t)wg * T_STEPS * G3W;

  float creg = 0.f;  // c state: threads tid<128 own (b=tid>>2, hc=tid&3)
  __syncthreads();

  for (int t = 0; t < T_STEPS; ++t) {
    // ---- prefetch XW row t (own contiguous block; normal cached loads) ---
    float2 xwA = {0.f, 0.f}, xwB = {0.f, 0.f};
    size_t aA = 0, aB = 0;
    if (hAct) {
      aA = (size_t)t * G3W + f00;
      aB = (size_t)t * G3W + f10;
      xwA = *(const float2*)&AXwg[aA];
      xwB = *(const float2*)&AXwg[aB];
    }
    double gxt = 0.0;
    if (tid == 0) gxt = gx[t];

    // ---- poll: all waves wait until all 64 flags reached t ---------------
    if (t > 0) {
      int guard = 0;
      for (;;) {
        const unsigned v = __hip_atomic_load(&flags[lane], __ATOMIC_RELAXED,
                                             __HIP_MEMORY_SCOPE_AGENT);
        if (__all((int)(v >= (unsigned)t))) break;
        if (++guard > (1 << 20)) break;  // hang guard (never trips normally)
      }
      asm volatile("" ::: "memory");
    }

    // ---- gather h_{t-1}: 8 batched dwordx4 bypass loads, ONE waitcnt -----
    {
      const uint64_t addr =
          (uint64_t)(hbank + (size_t)t * HSLICE) + (uint64_t)tid * 128u;
      float4 r0, r1, r2, r3, r4, r5, r6, r7;
      asm volatile(
          "global_load_dwordx4 %0, %8, off sc0 sc1\n\t"
          "global_load_dwordx4 %1, %8, off offset:16 sc0 sc1\n\t"
          "global_load_dwordx4 %2, %8, off offset:32 sc0 sc1\n\t"
          "global_load_dwordx4 %3, %8, off offset:48 sc0 sc1\n\t"
          "global_load_dwordx4 %4, %8, off offset:64 sc0 sc1\n\t"
          "global_load_dwordx4 %5, %8, off offset:80 sc0 sc1\n\t"
          "global_load_dwordx4 %6, %8, off offset:96 sc0 sc1\n\t"
          "global_load_dwordx4 %7, %8, off offset:112 sc0 sc1\n\t"
          "s_waitcnt vmcnt(0)"
          : "=&v"(r0), "=&v"(r1), "=&v"(r2), "=&v"(r3),
            "=&v"(r4), "=&v"(r5), "=&v"(r6), "=&v"(r7)
          : "v"(addr)
          : "memory");
      *(float4*)&hL[gbase + 0][gcol] = r0;
      *(float4*)&hL[gbase + 1][gcol] = r1;
      *(float4*)&hL[gbase + 2][gcol] = r2;
      *(float4*)&hL[gbase + 3][gcol] = r3;
      *(float4*)&hL[gbase + 4][gcol] = r4;
      *(float4*)&hL[gbase + 5][gcol] = r5;
      *(float4*)&hL[gbase + 6][gcol] = r6;
      *(float4*)&hL[gbase + 7][gcol] = r7;
    }
    __syncthreads();  // B: hL complete

    // ---- wave 0: recall gate (fp64) + a_rec prefetch ---------------------
    // ---- threads 64..159: h@U (2jc x 2b), a_cur = hU + XW ----------------
    if (tid < 64) {
      if (t >= OMEGA) {
        const int gb = tid & 31, kp = tid >> 5;
        double s = 0.0;
        const int k0 = kp * 128;
        for (int k = k0; k < k0 + 128; k += 4) {
          const float4 hv = *(const float4*)&hL[gb][k];
          const float4 uv = *(const float4*)&UrL[k];
          s = fma((double)hv.x, (double)uv.x, s);
          s = fma((double)hv.y, (double)uv.y, s);
          s = fma((double)hv.z, (double)uv.z, s);
          s = fma((double)hv.w, (double)uv.w, s);
        }
        s += __shfl_xor(s, 32, 64);
        double v = (double)PrL[gb] * s;
        v += __shfl_xor(v, 16, 64);
        v += __shfl_xor(v, 8, 64);
        v += __shfl_xor(v, 4, 64);
        v += __shfl_xor(v, 2, 64);
        v += __shfl_xor(v, 1, 64);
        int idx = 0;
        if (tid == 0) {
          const double g = gxt + v;
          const double gate = 1.0 / (1.0 + exp(-g));
          idx = (int)rint((double)t * gate);  // ties-to-even == jnp.round
          if (idx > t - 1) idx = t - 1;
          if (idx < 0) idx = 0;
        }
        idx = __shfl(idx, 0, 64);
        // a_rec = a_cur[idx]: contiguous 1.5KB block in our own AXc region
        const float* __restrict__ src = AXwg + (size_t)idx * G3W;
        float av[6];
#pragma unroll
        for (int j = 0; j < 6; ++j) av[j] = src[tid + j * 64];
#pragma unroll
        for (int j = 0; j < 6; ++j) {
          const int f = tid + j * 64;
          ars[f % JC][f / JC] = av[j];
        }
      }
    } else if (hAct) {
      float s00 = 0.f, s01 = 0.f, s10 = 0.f, s11 = 0.f;
      for (int k = 0; k < HDIM; k += 4) {
        const float4 u0 = *(const float4*)&ULt[jc0][k];  // 16-lane broadcast
        const float4 u1 = *(const float4*)&ULt[jc1][k];
        const float4 h0 = *(const float4*)&hL[bp][k];    // 4-lane broadcast
        const float4 h1 = *(const float4*)&hL[bp + 16][k];
        s00 = fmaf(h0.x, u0.x, s00); s00 = fmaf(h0.y, u0.y, s00);
        s00 = fmaf(h0.z, u0.z, s00); s00 = fmaf(h0.w, u0.w, s00);
        s01 = fmaf(h0.x, u1.x, s01); s01 = fmaf(h0.y, u1.y, s01);
        s01 = fmaf(h0.z, u1.z, s01); s01 = fmaf(h0.w, u1.w, s01);
        s10 = fmaf(h1.x, u0.x, s10); s10 = fmaf(h1.y, u0.y, s10);
        s10 = fmaf(h1.z, u0.z, s10); s10 = fmaf(h1.w, u0.w, s10);
        s11 = fmaf(h1.x, u1.x, s11); s11 = fmaf(h1.y, u1.y, s11);
        s11 = fmaf(h1.z, u1.z, s11); s11 = fmaf(h1.w, u1.w, s11);
      }
      const float v00 = s00 + xwA.x, v01 = s01 + xwA.y;
      const float v10 = s10 + xwB.x, v11 = s11 + xwB.y;
      *(float2*)&AXwg[aA] = make_float2(v00, v01);  // a_cur into bank
      *(float2*)&AXwg[aB] = make_float2(v10, v11);
      acs[jc0][bp] = v00;  acs[jc1][bp] = v01;
      acs[jc0][bp + 16] = v10;  acs[jc1][bp + 16] = v11;
      if (t < OMEGA) {  // use_self: a_rec == a_cur
        ars[jc0][bp] = v00;  ars[jc1][bp] = v01;
        ars[jc0][bp + 16] = v10;  ars[jc1][bp + 16] = v11;
      }
    }
    __syncthreads();  // C: acs/ars complete

    // ---- owner threads: gates = P @ [a_cur; a_rec] + bias, LSTM ----------
    if (tid < BSZ * HS) {
      float gi = biasL[ohc];
      float gf = biasL[4 + ohc];
      float gg = biasL[8 + ohc];
#pragma unroll
      for (int b4 = 0; b4 < BSZ; b4 += 4) {
        const float4 pv = *(const float4*)&PL[ob][b4];
        const float4 ai = *(const float4*)&acs[ohc][b4];
        const float4 af = *(const float4*)&acs[4 + ohc][b4];
        const float4 ag = *(const float4*)&acs[8 + ohc][b4];
        gi = fmaf(pv.x, ai.x, gi); gi = fmaf(pv.y, ai.y, gi);
        gi = fmaf(pv.z, ai.z, gi); gi = fmaf(pv.w, ai.w, gi);
        gf = fmaf(pv.x, af.x, gf); gf = fmaf(pv.y, af.y, gf);
        gf = fmaf(pv.z, af.z, gf); gf = fmaf(pv.w, af.w, gf);
        gg = fmaf(pv.x, ag.x, gg); gg = fmaf(pv.y, ag.y, gg);
        gg = fmaf(pv.z, ag.z, gg); gg = fmaf(pv.w, ag.w, gg);
      }
#pragma unroll
      for (int b4 = 0; b4 < BSZ; b4 += 4) {
        const float4 pv = *(const float4*)&PL[ob][BSZ + b4];
        const float4 ai = *(const float4*)&ars[ohc][b4];
        const float4 af = *(const float4*)&ars[4 + ohc][b4];
        const float4 ag = *(const float4*)&ars[8 + ohc][b4];
        gi = fmaf(pv.x, ai.x, gi); gi = fmaf(pv.y, ai.y, gi);
        gi = fmaf(pv.z, ai.z, gi); gi = fmaf(pv.w, ai.w, gi);
        gf = fmaf(pv.x, af.x, gf); gf = fmaf(pv.y, af.y, gf);
        gf = fmaf(pv.z, af.z, gf); gf = fmaf(pv.w, af.w, gf);
        gg = fmaf(pv.x, ag.x, gg); gg = fmaf(pv.y, ag.y, gg);
        gg = fmaf(pv.z, ag.z, gg); gg = fmaf(pv.w, ag.w, gg);
      }
      const float iv = 1.f / (1.f + expf(-gi));
      const float fv = 1.f / (1.f + expf(-gf));
      const float gv = tanhf(gg);
      creg = fmaf(fv, creg, iv * gv);
      hpub[tid] = iv * tanhf(creg);  // o_t = i_t (faithful to source)
    }
    __syncthreads();  // F: hpub complete

    // ---- wave 0 publishes slice (asm store + waitcnt) then flag ----------
    if (tid < 64) {
      const float2 val = *(const float2*)&hpub[lane * 2];
      const uint64_t daddr =
          (uint64_t)(hbank + (size_t)(t + 1) * HSLICE + (size_t)wg * (BSZ * HS)) +
          (uint64_t)lane * 8u;
      asm volatile(
          "global_store_dwordx2 %0, %1, off sc0 sc1\n\t"
          "s_waitcnt vmcnt(0)"
          :: "v"(daddr), "v"(val)
          : "memory");
      if (tid == 0) {
        __hip_atomic_store(&flags[wg], (unsigned)(t + 1), __ATOMIC_RELAXED,
                           __HIP_MEMORY_SCOPE_AGENT);
      }
    }
  }
}

// ------------------------------ Output -------------------------------------
__global__ void outK(const float* __restrict__ hbank, const float* __restrict__ W_out,
                     const float* __restrict__ b_out, float* __restrict__ out) {
  const int b = threadIdx.x;
  if (b < BSZ) {
    const float* h = hbank + (size_t)T_STEPS * HSLICE;  // [wg][b][c]
    float s = 0.f;
    for (int wg = 0; wg < KWG; ++wg) {
      const float4 hv = *(const float4*)&h[wg * (BSZ * HS) + b * HS];
      const float4 wv = *(const float4*)&W_out[wg * HS];
      s = fmaf(hv.x, wv.x, s); s = fmaf(hv.y, wv.y, s);
      s = fmaf(hv.z, wv.z, s); s = fmaf(hv.w, wv.w, s);
    }
    out[b] = s + b_out[0];
  }
}

// ------------------------------ Launch -------------------------------------
extern "C" void kernel_launch(void* const* d_in, const int* in_sizes, int n_in,
                              void* d_out, int out_size, void* d_ws, size_t ws_size,
                              hipStream_t stream) {
  const float* x      = (const float*)d_in[0];
  const float* W      = (const float*)d_in[1];
  const float* U      = (const float*)d_in[2];
  const float* P      = (const float*)d_in[3];
  const float* B_bias = (const float*)d_in[4];
  const float* W_r    = (const float*)d_in[5];
  const float* P_r    = (const float*)d_in[6];
  const float* U_r    = (const float*)d_in[7];
  const float* W_out  = (const float*)d_in[8];
  const float* b_out  = (const float*)d_in[9];

  char* ws = (char*)d_ws;
  float*    AXc   = (float*)ws;
  float*    hbank = (float*)(ws + AXC_BYTES);
  double*   gx    = (double*)(ws + AXC_BYTES + HB_BYTES);
  unsigned* flags = (unsigned*)(ws + AXC_BYTES + HB_BYTES + GX_BYTES);

  hipMemsetAsync(hbank, 0, (size_t)HSLICE * sizeof(float), stream);  // h0 = 0
  hipMemsetAsync(flags, 0, (size_t)KWG * sizeof(unsigned), stream);

  phaseA<<<T_STEPS, 256, 0, stream>>>(x, W, W_r, P_r, AXc, gx);
  phaseB<<<KWG, 256, 0, stream>>>(U, P, B_bias, P_r, U_r, AXc, hbank, gx, flags);
  outK<<<1, 64, 0, stream>>>(hbank, W_out, b_out, (float*)d_out);
}

// Round 6
// 9065.965 us; speedup vs baseline: 1.0827x; 1.0827x over previous
//
#include <hip/hip_runtime.h>
#include <cstdint>
#include <cstddef>

// ---------------------------------------------------------------------------
// RLSTM: B=32, T=1024, F=256, H=256.
// Identities: a_rec = a_cur[idx]; gate chunk 4 unused (o_t = i_t); x@W is
// recurrence-free (phase A). Phase B: 64 persistent WGs, each owns 4 h-cols
// (12 gate cols). R6: R5's gather was batched but UNCOALESCED (lane stride
// 128B -> 64 lines per instr -> 2048 sparse 16B MALL transactions/WG-step).
// Fix: lane-stride-16B layout -- instr j at base + tid*16 + j*4096 (8 VGPR
// addresses; imm offset can't hold 4096), 1KB contiguous per wave per instr,
// ONE s_waitcnt. Everything else identical to R5.
// ---------------------------------------------------------------------------

#define T_STEPS 1024
#define BSZ 32
#define FDIM 256
#define HDIM 256
#define G3W 384          // per-WG gate cols x batch (12*32) flat row
#define KWG 64           // phase-B workgroups (co-resident on 256 CUs)
#define HS 4             // h-cols per WG
#define JC 12            // gate cols per WG (3 chunks x HS)
#define HPAD 260         // LDS row pad
#define OMEGA 32
#define HSLICE 8192      // floats per hbank step slice (32*256)

static const size_t AXC_BYTES = (size_t)KWG * T_STEPS * G3W * sizeof(float);      // 96 MiB
static const size_t HB_BYTES  = (size_t)(T_STEPS + 1) * HSLICE * sizeof(float);   // 32 MiB
static const size_t GX_BYTES  = (size_t)T_STEPS * sizeof(double);

// ------------------------------ Phase A ------------------------------------
__global__ __launch_bounds__(256) void phaseA(const float* __restrict__ x,
                                              const float* __restrict__ W,
                                              const float* __restrict__ W_r,
                                              const float* __restrict__ P_r,
                                              float* __restrict__ AXc,
                                              double* __restrict__ gx) {
  const int t = blockIdx.x;
  const int tid = threadIdx.x;
  __shared__ __align__(16) float xs[BSZ][HPAD];
  __shared__ double sred[BSZ];

  for (int i = tid; i < BSZ * FDIM / 4; i += 256) {
    const int b = (i * 4) >> 8;
    const int k = (i * 4) & 255;
    *(float4*)&xs[b][k] = *(const float4*)&x[((size_t)b * T_STEPS + t) * FDIM + k];
  }
  __syncthreads();

  for (int pass = 0; pass < 3; ++pass) {
    const int j = pass * 256 + tid;           // gate col in [0,768)
    float acc[BSZ];
#pragma unroll
    for (int b = 0; b < BSZ; ++b) acc[b] = 0.f;
    for (int k0 = 0; k0 < FDIM; k0 += 4) {
      const float w0 = W[(size_t)(k0 + 0) * 1024 + j];
      const float w1 = W[(size_t)(k0 + 1) * 1024 + j];
      const float w2 = W[(size_t)(k0 + 2) * 1024 + j];
      const float w3 = W[(size_t)(k0 + 3) * 1024 + j];
#pragma unroll
      for (int b = 0; b < BSZ; ++b) {
        const float4 xv = *(const float4*)&xs[b][k0];  // LDS broadcast
        acc[b] = fmaf(xv.x, w0, acc[b]);
        acc[b] = fmaf(xv.y, w1, acc[b]);
        acc[b] = fmaf(xv.z, w2, acc[b]);
        acc[b] = fmaf(xv.w, w3, acc[b]);
      }
    }
    // AXc[wg][t][b*12 + slot], wg = (j%256)/4, slot = (j/256)*4 + j%4
    const int wgj = (j >> 2) & 63;
    const int slot = ((j >> 8) << 2) | (j & 3);
    float* dst = AXc + ((size_t)wgj * T_STEPS + t) * G3W + slot;
    for (int b = 0; b < BSZ; ++b) dst[b * 12] = acc[b];
  }

  if (tid < BSZ) {
    double s = 0.0;
    for (int k = 0; k < FDIM; k += 4) {
      const float4 xv = *(const float4*)&xs[tid][k];
      const float4 wv = *(const float4*)&W_r[k];
      s = fma((double)xv.x, (double)wv.x, s);
      s = fma((double)xv.y, (double)wv.y, s);
      s = fma((double)xv.z, (double)wv.z, s);
      s = fma((double)xv.w, (double)wv.w, s);
    }
    sred[tid] = s;
  }
  __syncthreads();
  if (tid == 0) {
    double g = 0.0;
    for (int b = 0; b < BSZ; ++b) g = fma((double)P_r[b], sred[b], g);
    gx[t] = g;
  }
}

// ------------------------------ Phase B ------------------------------------
__global__ __launch_bounds__(256) void phaseB(const float* __restrict__ U,
                                              const float* __restrict__ P,
                                              const float* __restrict__ B_bias,
                                              const float* __restrict__ P_r,
                                              const float* __restrict__ U_r,
                                              float* __restrict__ AXc,
                                              float* __restrict__ hbank,
                                              const double* __restrict__ gx,
                                              unsigned int* __restrict__ flags) {
  const int wg = blockIdx.x;
  const int tid = threadIdx.x;
  const int lane = tid & 63;

  __shared__ __align__(16) float ULt[JC][HPAD];   // U cols for this WG, k-major
  __shared__ __align__(16) float hL[BSZ][HPAD];   // h_{t-1}, full
  __shared__ __align__(16) float PL[BSZ][64];
  __shared__ __align__(16) float acs[JC][36];     // a_cur slice [jc][b]
  __shared__ __align__(16) float ars[JC][36];     // a_rec slice
  __shared__ __align__(16) float hpub[BSZ * HS];  // our h slice [b*4+c]
  __shared__ __align__(16) float UrL[FDIM];
  __shared__ float PrL[BSZ];
  __shared__ float biasL[JC];

  for (int i = tid; i < JC * HDIM; i += 256) {
    const int jc = i >> 8, k = i & 255;
    const int col = (jc >> 2) * HDIM + wg * HS + (jc & 3);
    ULt[jc][k] = U[(size_t)k * 1024 + col];
  }
  for (int i = tid; i < BSZ * 64; i += 256) PL[i >> 6][i & 63] = P[i];
  if (tid < FDIM) UrL[tid] = U_r[tid];
  if (tid < BSZ) PrL[tid] = P_r[tid];
  if (tid < JC) biasL[tid] = B_bias[(tid >> 2) * HDIM + wg * HS + (tid & 3)];

  // h@U mapping: threads 64..159 (96 active), 2jc x 2b register block.
  const int hs = tid - 64;
  const bool hAct = (tid >= 64) && (tid < 160);
  const int jp = (hs >> 4) % 6;            // [0,6)
  const int bp = hs & 15;                  // [0,16)
  const int jc0 = 2 * jp, jc1 = 2 * jp + 1;
  const int f00 = bp * 12 + jc0;           // flat (b,jc) for b=bp
  const int f10 = (bp + 16) * 12 + jc0;    // for b=bp+16

  const int ob = tid >> 2, ohc = tid & 3;  // owner mapping (tid<128)
  // gather scatter mapping (coalesced): instr j covers dwords
  // d = tid*4 + j*1024 -> hL[tid&31][4*(tid>>5) + 32*j]
  const int grow = tid & 31;
  const int gc0 = (tid >> 5) * 4;

  float* __restrict__ AXwg = AXc + (size_t)wg * T_STEPS * G3W;

  float creg = 0.f;  // c state: threads tid<128 own (b=tid>>2, hc=tid&3)
  __syncthreads();

  for (int t = 0; t < T_STEPS; ++t) {
    // ---- prefetch XW row t (own contiguous block; normal cached loads) ---
    float2 xwA = {0.f, 0.f}, xwB = {0.f, 0.f};
    size_t aA = 0, aB = 0;
    if (hAct) {
      aA = (size_t)t * G3W + f00;
      aB = (size_t)t * G3W + f10;
      xwA = *(const float2*)&AXwg[aA];
      xwB = *(const float2*)&AXwg[aB];
    }
    double gxt = 0.0;
    if (tid == 0) gxt = gx[t];

    // ---- poll: all waves wait until all 64 flags reached t ---------------
    if (t > 0) {
      int guard = 0;
      for (;;) {
        const unsigned v = __hip_atomic_load(&flags[lane], __ATOMIC_RELAXED,
                                             __HIP_MEMORY_SCOPE_AGENT);
        if (__all((int)(v >= (unsigned)t))) break;
        if (++guard > (1 << 20)) break;  // hang guard (never trips normally)
      }
      asm volatile("" ::: "memory");
    }

    // ---- gather h_{t-1}: 8 coalesced dwordx4 bypass loads, ONE waitcnt ---
    // instr j: lanes at base + tid*16 + j*4096 -> 1KB contiguous per wave.
    {
      const uint64_t base =
          (uint64_t)(hbank + (size_t)t * HSLICE) + (uint64_t)tid * 16u;
      const uint64_t a0 = base;
      const uint64_t a1 = base + 4096u;
      const uint64_t a2 = base + 8192u;
      const uint64_t a3 = base + 12288u;
      const uint64_t a4 = base + 16384u;
      const uint64_t a5 = base + 20480u;
      const uint64_t a6 = base + 24576u;
      const uint64_t a7 = base + 28672u;
      float4 r0, r1, r2, r3, r4, r5, r6, r7;
      asm volatile(
          "global_load_dwordx4 %0, %8, off sc0 sc1\n\t"
          "global_load_dwordx4 %1, %9, off sc0 sc1\n\t"
          "global_load_dwordx4 %2, %10, off sc0 sc1\n\t"
          "global_load_dwordx4 %3, %11, off sc0 sc1\n\t"
          "global_load_dwordx4 %4, %12, off sc0 sc1\n\t"
          "global_load_dwordx4 %5, %13, off sc0 sc1\n\t"
          "global_load_dwordx4 %6, %14, off sc0 sc1\n\t"
          "global_load_dwordx4 %7, %15, off sc0 sc1\n\t"
          "s_waitcnt vmcnt(0)"
          : "=&v"(r0), "=&v"(r1), "=&v"(r2), "=&v"(r3),
            "=&v"(r4), "=&v"(r5), "=&v"(r6), "=&v"(r7)
          : "v"(a0), "v"(a1), "v"(a2), "v"(a3),
            "v"(a4), "v"(a5), "v"(a6), "v"(a7)
          : "memory");
      *(float4*)&hL[grow][gc0 + 0]   = r0;
      *(float4*)&hL[grow][gc0 + 32]  = r1;
      *(float4*)&hL[grow][gc0 + 64]  = r2;
      *(float4*)&hL[grow][gc0 + 96]  = r3;
      *(float4*)&hL[grow][gc0 + 128] = r4;
      *(float4*)&hL[grow][gc0 + 160] = r5;
      *(float4*)&hL[grow][gc0 + 192] = r6;
      *(float4*)&hL[grow][gc0 + 224] = r7;
    }
    __syncthreads();  // B: hL complete

    // ---- wave 0: recall gate (fp64) + a_rec prefetch ---------------------
    // ---- threads 64..159: h@U (2jc x 2b), a_cur = hU + XW ----------------
    if (tid < 64) {
      if (t >= OMEGA) {
        const int gb = tid & 31, kp = tid >> 5;
        double s = 0.0;
        const int k0 = kp * 128;
        for (int k = k0; k < k0 + 128; k += 4) {
          const float4 hv = *(const float4*)&hL[gb][k];
          const float4 uv = *(const float4*)&UrL[k];
          s = fma((double)hv.x, (double)uv.x, s);
          s = fma((double)hv.y, (double)uv.y, s);
          s = fma((double)hv.z, (double)uv.z, s);
          s = fma((double)hv.w, (double)uv.w, s);
        }
        s += __shfl_xor(s, 32, 64);
        double v = (double)PrL[gb] * s;
        v += __shfl_xor(v, 16, 64);
        v += __shfl_xor(v, 8, 64);
        v += __shfl_xor(v, 4, 64);
        v += __shfl_xor(v, 2, 64);
        v += __shfl_xor(v, 1, 64);
        int idx = 0;
        if (tid == 0) {
          const double g = gxt + v;
          const double gate = 1.0 / (1.0 + exp(-g));
          idx = (int)rint((double)t * gate);  // ties-to-even == jnp.round
          if (idx > t - 1) idx = t - 1;
          if (idx < 0) idx = 0;
        }
        idx = __shfl(idx, 0, 64);
        // a_rec = a_cur[idx]: contiguous 1.5KB block in our own AXc region
        const float* __restrict__ src = AXwg + (size_t)idx * G3W;
        float av[6];
#pragma unroll
        for (int j = 0; j < 6; ++j) av[j] = src[tid + j * 64];
#pragma unroll
        for (int j = 0; j < 6; ++j) {
          const int f = tid + j * 64;
          ars[f % JC][f / JC] = av[j];
        }
      }
    } else if (hAct) {
      float s00 = 0.f, s01 = 0.f, s10 = 0.f, s11 = 0.f;
      for (int k = 0; k < HDIM; k += 4) {
        const float4 u0 = *(const float4*)&ULt[jc0][k];  // 16-lane broadcast
        const float4 u1 = *(const float4*)&ULt[jc1][k];
        const float4 h0 = *(const float4*)&hL[bp][k];    // 4-lane broadcast
        const float4 h1 = *(const float4*)&hL[bp + 16][k];
        s00 = fmaf(h0.x, u0.x, s00); s00 = fmaf(h0.y, u0.y, s00);
        s00 = fmaf(h0.z, u0.z, s00); s00 = fmaf(h0.w, u0.w, s00);
        s01 = fmaf(h0.x, u1.x, s01); s01 = fmaf(h0.y, u1.y, s01);
        s01 = fmaf(h0.z, u1.z, s01); s01 = fmaf(h0.w, u1.w, s01);
        s10 = fmaf(h1.x, u0.x, s10); s10 = fmaf(h1.y, u0.y, s10);
        s10 = fmaf(h1.z, u0.z, s10); s10 = fmaf(h1.w, u0.w, s10);
        s11 = fmaf(h1.x, u1.x, s11); s11 = fmaf(h1.y, u1.y, s11);
        s11 = fmaf(h1.z, u1.z, s11); s11 = fmaf(h1.w, u1.w, s11);
      }
      const float v00 = s00 + xwA.x, v01 = s01 + xwA.y;
      const float v10 = s10 + xwB.x, v11 = s11 + xwB.y;
      *(float2*)&AXwg[aA] = make_float2(v00, v01);  // a_cur into bank
      *(float2*)&AXwg[aB] = make_float2(v10, v11);
      acs[jc0][bp] = v00;  acs[jc1][bp] = v01;
      acs[jc0][bp + 16] = v10;  acs[jc1][bp + 16] = v11;
      if (t < OMEGA) {  // use_self: a_rec == a_cur
        ars[jc0][bp] = v00;  ars[jc1][bp] = v01;
        ars[jc0][bp + 16] = v10;  ars[jc1][bp + 16] = v11;
      }
    }
    __syncthreads();  // C: acs/ars complete

    // ---- owner threads: gates = P @ [a_cur; a_rec] + bias, LSTM ----------
    if (tid < BSZ * HS) {
      float gi = biasL[ohc];
      float gf = biasL[4 + ohc];
      float gg = biasL[8 + ohc];
#pragma unroll
      for (int b4 = 0; b4 < BSZ; b4 += 4) {
        const float4 pv = *(const float4*)&PL[ob][b4];
        const float4 ai = *(const float4*)&acs[ohc][b4];
        const float4 af = *(const float4*)&acs[4 + ohc][b4];
        const float4 ag = *(const float4*)&acs[8 + ohc][b4];
        gi = fmaf(pv.x, ai.x, gi); gi = fmaf(pv.y, ai.y, gi);
        gi = fmaf(pv.z, ai.z, gi); gi = fmaf(pv.w, ai.w, gi);
        gf = fmaf(pv.x, af.x, gf); gf = fmaf(pv.y, af.y, gf);
        gf = fmaf(pv.z, af.z, gf); gf = fmaf(pv.w, af.w, gf);
        gg = fmaf(pv.x, ag.x, gg); gg = fmaf(pv.y, ag.y, gg);
        gg = fmaf(pv.w, ag.w, fmaf(pv.z, ag.z, gg));
      }
#pragma unroll
      for (int b4 = 0; b4 < BSZ; b4 += 4) {
        const float4 pv = *(const float4*)&PL[ob][BSZ + b4];
        const float4 ai = *(const float4*)&ars[ohc][b4];
        const float4 af = *(const float4*)&ars[4 + ohc][b4];
        const float4 ag = *(const float4*)&ars[8 + ohc][b4];
        gi = fmaf(pv.x, ai.x, gi); gi = fmaf(pv.y, ai.y, gi);
        gi = fmaf(pv.z, ai.z, gi); gi = fmaf(pv.w, ai.w, gi);
        gf = fmaf(pv.x, af.x, gf); gf = fmaf(pv.y, af.y, gf);
        gf = fmaf(pv.z, af.z, gf); gf = fmaf(pv.w, af.w, gf);
        gg = fmaf(pv.x, ag.x, gg); gg = fmaf(pv.y, ag.y, gg);
        gg = fmaf(pv.w, ag.w, fmaf(pv.z, ag.z, gg));
      }
      const float iv = 1.f / (1.f + expf(-gi));
      const float fv = 1.f / (1.f + expf(-gf));
      const float gv = tanhf(gg);
      creg = fmaf(fv, creg, iv * gv);
      hpub[tid] = iv * tanhf(creg);  // o_t = i_t (faithful to source)
    }
    __syncthreads();  // F: hpub complete

    // ---- wave 0 publishes slice (asm store + waitcnt) then flag ----------
    if (tid < 64) {
      const float2 val = *(const float2*)&hpub[lane * 2];
      const uint64_t daddr =
          (uint64_t)(hbank + (size_t)(t + 1) * HSLICE + (size_t)wg * (BSZ * HS)) +
          (uint64_t)lane * 8u;
      asm volatile(
          "global_store_dwordx2 %0, %1, off sc0 sc1\n\t"
          "s_waitcnt vmcnt(0)"
          :: "v"(daddr), "v"(val)
          : "memory");
      if (tid == 0) {
        __hip_atomic_store(&flags[wg], (unsigned)(t + 1), __ATOMIC_RELAXED,
                           __HIP_MEMORY_SCOPE_AGENT);
      }
    }
  }
}

// ------------------------------ Output -------------------------------------
__global__ void outK(const float* __restrict__ hbank, const float* __restrict__ W_out,
                     const float* __restrict__ b_out, float* __restrict__ out) {
  const int b = threadIdx.x;
  if (b < BSZ) {
    const float* h = hbank + (size_t)T_STEPS * HSLICE;  // [wg][b][c]
    float s = 0.f;
    for (int wg = 0; wg < KWG; ++wg) {
      const float4 hv = *(const float4*)&h[wg * (BSZ * HS) + b * HS];
      const float4 wv = *(const float4*)&W_out[wg * HS];
      s = fmaf(hv.x, wv.x, s); s = fmaf(hv.y, wv.y, s);
      s = fmaf(hv.z, wv.z, s); s = fmaf(hv.w, wv.w, s);
    }
    out[b] = s + b_out[0];
  }
}

// ------------------------------ Launch -------------------------------------
extern "C" void kernel_launch(void* const* d_in, const int* in_sizes, int n_in,
                              void* d_out, int out_size, void* d_ws, size_t ws_size,
                              hipStream_t stream) {
  const float* x      = (const float*)d_in[0];
  const float* W      = (const float*)d_in[1];
  const float* U      = (const float*)d_in[2];
  const float* P      = (const float*)d_in[3];
  const float* B_bias = (const float*)d_in[4];
  const float* W_r    = (const float*)d_in[5];
  const float* P_r    = (const float*)d_in[6];
  const float* U_r    = (const float*)d_in[7];
  const float* W_out  = (const float*)d_in[8];
  const float* b_out  = (const float*)d_in[9];

  char* ws = (char*)d_ws;
  float*    AXc   = (float*)ws;
  float*    hbank = (float*)(ws + AXC_BYTES);
  double*   gx    = (double*)(ws + AXC_BYTES + HB_BYTES);
  unsigned* flags = (unsigned*)(ws + AXC_BYTES + HB_BYTES + GX_BYTES);

  hipMemsetAsync(hbank, 0, (size_t)HSLICE * sizeof(float), stream);  // h0 = 0
  hipMemsetAsync(flags, 0, (size_t)KWG * sizeof(unsigned), stream);

  phaseA<<<T_STEPS, 256, 0, stream>>>(x, W, W_r, P_r, AXc, gx);
  phaseB<<<KWG, 256, 0, stream>>>(U, P, B_bias, P_r, U_r, AXc, hbank, gx, flags);
  outK<<<1, 64, 0, stream>>>(hbank, W_out, b_out, (float*)d_out);
}

// Round 8
// 6059.138 us; speedup vs baseline: 1.6200x; 1.4962x over previous
//
#include <hip/hip_runtime.h>
#include <cstdint>
#include <cstddef>

// ---------------------------------------------------------------------------
// RLSTM: B=32, T=1024, F=256, H=256.
// Identities: a_rec = a_cur[idx]; gate chunk 4 unused (o_t = i_t); x@W is
// recurrence-free (phase A). Phase B: 64 persistent WGs, each owns 4 h-cols
// (12 gate cols). R8 (= R7 fixed): sync-contention attack --
//   * ONE cumulative atomic counter (1 line) replaces 64 flag words.
//   * Only wave 0 polls; waves 1-3 park at a barrier.
//   * h@U on R3's 192-thread/3-wave map.
//   * Batched coalesced sc0sc1 gather, single waitcnt.
//   * Publish: 64 lanes x dwordx2 (float4 asm INPUT miscompiles: "indirect
//     register inputs" -- 64-bit float2 inputs are the widest that work).
// Per-output fmaf chains unchanged -> absmax 0.0.
// ---------------------------------------------------------------------------

#define T_STEPS 1024
#define BSZ 32
#define FDIM 256
#define HDIM 256
#define G3W 384          // per-WG gate cols x batch (12*32) flat row
#define KWG 64           // phase-B workgroups (co-resident on 256 CUs)
#define HS 4             // h-cols per WG
#define JC 12            // gate cols per WG (3 chunks x HS)
#define HPAD 260         // LDS row pad
#define OMEGA 32
#define HSLICE 8192      // floats per hbank step slice (32*256)

static const size_t AXC_BYTES = (size_t)KWG * T_STEPS * G3W * sizeof(float);      // 96 MiB
static const size_t HB_BYTES  = (size_t)(T_STEPS + 1) * HSLICE * sizeof(float);   // 32 MiB
static const size_t GX_BYTES  = (size_t)T_STEPS * sizeof(double);

// ------------------------------ Phase A ------------------------------------
__global__ __launch_bounds__(256) void phaseA(const float* __restrict__ x,
                                              const float* __restrict__ W,
                                              const float* __restrict__ W_r,
                                              const float* __restrict__ P_r,
                                              float* __restrict__ AXc,
                                              double* __restrict__ gx) {
  const int t = blockIdx.x;
  const int tid = threadIdx.x;
  __shared__ __align__(16) float xs[BSZ][HPAD];
  __shared__ double sred[BSZ];

  for (int i = tid; i < BSZ * FDIM / 4; i += 256) {
    const int b = (i * 4) >> 8;
    const int k = (i * 4) & 255;
    *(float4*)&xs[b][k] = *(const float4*)&x[((size_t)b * T_STEPS + t) * FDIM + k];
  }
  __syncthreads();

  for (int pass = 0; pass < 3; ++pass) {
    const int j = pass * 256 + tid;           // gate col in [0,768)
    float acc[BSZ];
#pragma unroll
    for (int b = 0; b < BSZ; ++b) acc[b] = 0.f;
    for (int k0 = 0; k0 < FDIM; k0 += 4) {
      const float w0 = W[(size_t)(k0 + 0) * 1024 + j];
      const float w1 = W[(size_t)(k0 + 1) * 1024 + j];
      const float w2 = W[(size_t)(k0 + 2) * 1024 + j];
      const float w3 = W[(size_t)(k0 + 3) * 1024 + j];
#pragma unroll
      for (int b = 0; b < BSZ; ++b) {
        const float4 xv = *(const float4*)&xs[b][k0];  // LDS broadcast
        acc[b] = fmaf(xv.x, w0, acc[b]);
        acc[b] = fmaf(xv.y, w1, acc[b]);
        acc[b] = fmaf(xv.z, w2, acc[b]);
        acc[b] = fmaf(xv.w, w3, acc[b]);
      }
    }
    // AXc[wg][t][b*12 + slot], wg = (j%256)/4, slot = (j/256)*4 + j%4
    const int wgj = (j >> 2) & 63;
    const int slot = ((j >> 8) << 2) | (j & 3);
    float* dst = AXc + ((size_t)wgj * T_STEPS + t) * G3W + slot;
    for (int b = 0; b < BSZ; ++b) dst[b * 12] = acc[b];
  }

  if (tid < BSZ) {
    double s = 0.0;
    for (int k = 0; k < FDIM; k += 4) {
      const float4 xv = *(const float4*)&xs[tid][k];
      const float4 wv = *(const float4*)&W_r[k];
      s = fma((double)xv.x, (double)wv.x, s);
      s = fma((double)xv.y, (double)wv.y, s);
      s = fma((double)xv.z, (double)wv.z, s);
      s = fma((double)xv.w, (double)wv.w, s);
    }
    sred[tid] = s;
  }
  __syncthreads();
  if (tid == 0) {
    double g = 0.0;
    for (int b = 0; b < BSZ; ++b) g = fma((double)P_r[b], sred[b], g);
    gx[t] = g;
  }
}

// ------------------------------ Phase B ------------------------------------
__global__ __launch_bounds__(256) void phaseB(const float* __restrict__ U,
                                              const float* __restrict__ P,
                                              const float* __restrict__ B_bias,
                                              const float* __restrict__ P_r,
                                              const float* __restrict__ U_r,
                                              float* __restrict__ AXc,
                                              float* __restrict__ hbank,
                                              const double* __restrict__ gx,
                                              unsigned int* __restrict__ cnt) {
  const int wg = blockIdx.x;
  const int tid = threadIdx.x;

  __shared__ __align__(16) float ULt[JC][HPAD];   // U cols for this WG, k-major
  __shared__ __align__(16) float hL[BSZ][HPAD];   // h_{t-1}, full
  __shared__ __align__(16) float PL[BSZ][64];
  __shared__ __align__(16) float acs[JC][36];     // a_cur slice [jc][b]
  __shared__ __align__(16) float ars[JC][36];     // a_rec slice
  __shared__ __align__(16) float hpub[BSZ * HS];  // our h slice [b*4+c]
  __shared__ __align__(16) float UrL[FDIM];
  __shared__ float PrL[BSZ];
  __shared__ float biasL[JC];

  for (int i = tid; i < JC * HDIM; i += 256) {
    const int jc = i >> 8, k = i & 255;
    const int col = (jc >> 2) * HDIM + wg * HS + (jc & 3);
    ULt[jc][k] = U[(size_t)k * 1024 + col];
  }
  for (int i = tid; i < BSZ * 64; i += 256) PL[i >> 6][i & 63] = P[i];
  if (tid < FDIM) UrL[tid] = U_r[tid];
  if (tid < BSZ) PrL[tid] = P_r[tid];
  if (tid < JC) biasL[tid] = B_bias[(tid >> 2) * HDIM + wg * HS + (tid & 3)];

  // h@U mapping (R3): threads 64..255, u in [0,192): bA=u/12, jcA=u%12,
  // outputs (bA, bA+16) -- one ULt column read serves both.
  const int u = (tid >= 64) ? (tid - 64) : 0;
  const int bA = u / JC, jcA = u % JC;
  const int bB = bA + 16;
  const int f00 = bA * JC + jcA;           // flat (b,jc) index in AXc row
  const int f10 = bB * JC + jcA;

  const int ob = tid >> 2, ohc = tid & 3;  // owner mapping (tid<128)
  // gather scatter mapping (coalesced): instr j covers dwords
  // d = tid*4 + j*1024 -> hL[tid&31][4*(tid>>5) + 32*j]
  const int grow = tid & 31;
  const int gc0 = (tid >> 5) * 4;

  float* __restrict__ AXwg = AXc + (size_t)wg * T_STEPS * G3W;

  float creg = 0.f;  // c state: threads tid<128 own (b=tid>>2, hc=tid&3)
  __syncthreads();

  for (int t = 0; t < T_STEPS; ++t) {
    // ---- prefetch XW row t (own contiguous block; normal cached loads) ---
    float xw0 = 0.f, xw1 = 0.f;
    size_t aA = 0, aB = 0;
    if (tid >= 64) {
      aA = (size_t)t * G3W + f00;
      aB = (size_t)t * G3W + f10;
      xw0 = AXwg[aA];
      xw1 = AXwg[aB];
    }
    double gxt = 0.0;
    if (tid == 0) gxt = gx[t];

    // ---- wave 0 polls the single counter; others park at barrier A -------
    if (t > 0) {
      if (tid < 64) {
        const unsigned tgt = 64u * (unsigned)t;
        int guard = 0;
        while (__hip_atomic_load(cnt, __ATOMIC_RELAXED,
                                 __HIP_MEMORY_SCOPE_AGENT) < tgt) {
          if (++guard > (1 << 20)) break;  // hang guard (never trips normally)
        }
      }
      __syncthreads();  // A
      asm volatile("" ::: "memory");  // no hoisting loads above the poll
    }

    // ---- gather h_{t-1}: 8 coalesced dwordx4 bypass loads, ONE waitcnt ---
    {
      const uint64_t base =
          (uint64_t)(hbank + (size_t)t * HSLICE) + (uint64_t)tid * 16u;
      const uint64_t a0 = base;
      const uint64_t a1 = base + 4096u;
      const uint64_t a2 = base + 8192u;
      const uint64_t a3 = base + 12288u;
      const uint64_t a4 = base + 16384u;
      const uint64_t a5 = base + 20480u;
      const uint64_t a6 = base + 24576u;
      const uint64_t a7 = base + 28672u;
      float4 r0, r1, r2, r3, r4, r5, r6, r7;
      asm volatile(
          "global_load_dwordx4 %0, %8, off sc0 sc1\n\t"
          "global_load_dwordx4 %1, %9, off sc0 sc1\n\t"
          "global_load_dwordx4 %2, %10, off sc0 sc1\n\t"
          "global_load_dwordx4 %3, %11, off sc0 sc1\n\t"
          "global_load_dwordx4 %4, %12, off sc0 sc1\n\t"
          "global_load_dwordx4 %5, %13, off sc0 sc1\n\t"
          "global_load_dwordx4 %6, %14, off sc0 sc1\n\t"
          "global_load_dwordx4 %7, %15, off sc0 sc1\n\t"
          "s_waitcnt vmcnt(0)"
          : "=&v"(r0), "=&v"(r1), "=&v"(r2), "=&v"(r3),
            "=&v"(r4), "=&v"(r5), "=&v"(r6), "=&v"(r7)
          : "v"(a0), "v"(a1), "v"(a2), "v"(a3),
            "v"(a4), "v"(a5), "v"(a6), "v"(a7)
          : "memory");
      *(float4*)&hL[grow][gc0 + 0]   = r0;
      *(float4*)&hL[grow][gc0 + 32]  = r1;
      *(float4*)&hL[grow][gc0 + 64]  = r2;
      *(float4*)&hL[grow][gc0 + 96]  = r3;
      *(float4*)&hL[grow][gc0 + 128] = r4;
      *(float4*)&hL[grow][gc0 + 160] = r5;
      *(float4*)&hL[grow][gc0 + 192] = r6;
      *(float4*)&hL[grow][gc0 + 224] = r7;
    }
    __syncthreads();  // B: hL complete

    // ---- wave 0: recall gate (fp64) + a_rec prefetch ---------------------
    // ---- threads 64..255 (3 waves): h@U full-K, a_cur = hU + XW ----------
    if (tid < 64) {
      if (t >= OMEGA) {
        const int gb = tid & 31, kp = tid >> 5;
        double s = 0.0;
        const int k0 = kp * 128;
        for (int k = k0; k < k0 + 128; k += 4) {
          const float4 hv = *(const float4*)&hL[gb][k];
          const float4 uv = *(const float4*)&UrL[k];
          s = fma((double)hv.x, (double)uv.x, s);
          s = fma((double)hv.y, (double)uv.y, s);
          s = fma((double)hv.z, (double)uv.z, s);
          s = fma((double)hv.w, (double)uv.w, s);
        }
        s += __shfl_xor(s, 32, 64);
        double v = (double)PrL[gb] * s;
        v += __shfl_xor(v, 16, 64);
        v += __shfl_xor(v, 8, 64);
        v += __shfl_xor(v, 4, 64);
        v += __shfl_xor(v, 2, 64);
        v += __shfl_xor(v, 1, 64);
        int idx = 0;
        if (tid == 0) {
          const double g = gxt + v;
          const double gate = 1.0 / (1.0 + exp(-g));
          idx = (int)rint((double)t * gate);  // ties-to-even == jnp.round
          if (idx > t - 1) idx = t - 1;
          if (idx < 0) idx = 0;
        }
        idx = __shfl(idx, 0, 64);
        // a_rec = a_cur[idx]: contiguous 1.5KB block in our own AXc region
        const float* __restrict__ src = AXwg + (size_t)idx * G3W;
        float av[6];
#pragma unroll
        for (int j = 0; j < 6; ++j) av[j] = src[tid + j * 64];
#pragma unroll
        for (int j = 0; j < 6; ++j) {
          const int f = tid + j * 64;
          ars[f % JC][f / JC] = av[j];
        }
      }
    } else {
      float s0 = 0.f, s1 = 0.f;
      for (int k = 0; k < HDIM; k += 4) {
        const float4 uv = *(const float4*)&ULt[jcA][k];
        const float4 h0 = *(const float4*)&hL[bA][k];
        const float4 h1 = *(const float4*)&hL[bB][k];
        s0 = fmaf(h0.x, uv.x, s0); s0 = fmaf(h0.y, uv.y, s0);
        s0 = fmaf(h0.z, uv.z, s0); s0 = fmaf(h0.w, uv.w, s0);
        s1 = fmaf(h1.x, uv.x, s1); s1 = fmaf(h1.y, uv.y, s1);
        s1 = fmaf(h1.z, uv.z, s1); s1 = fmaf(h1.w, uv.w, s1);
      }
      const float v0 = s0 + xw0;
      const float v1 = s1 + xw1;
      AXwg[aA] = v0;            // a_cur into bank (read back later as a_rec)
      AXwg[aB] = v1;
      acs[jcA][bA] = v0;
      acs[jcA][bB] = v1;
      if (t < OMEGA) {          // use_self: a_rec == a_cur
        ars[jcA][bA] = v0;
        ars[jcA][bB] = v1;
      }
    }
    __syncthreads();  // C: acs/ars complete

    // ---- owner threads: gates = P @ [a_cur; a_rec] + bias, LSTM ----------
    if (tid < BSZ * HS) {
      float gi = biasL[ohc];
      float gf = biasL[4 + ohc];
      float gg = biasL[8 + ohc];
#pragma unroll
      for (int b4 = 0; b4 < BSZ; b4 += 4) {
        const float4 pv = *(const float4*)&PL[ob][b4];
        const float4 ai = *(const float4*)&acs[ohc][b4];
        const float4 af = *(const float4*)&acs[4 + ohc][b4];
        const float4 ag = *(const float4*)&acs[8 + ohc][b4];
        gi = fmaf(pv.x, ai.x, gi); gi = fmaf(pv.y, ai.y, gi);
        gi = fmaf(pv.z, ai.z, gi); gi = fmaf(pv.w, ai.w, gi);
        gf = fmaf(pv.x, af.x, gf); gf = fmaf(pv.y, af.y, gf);
        gf = fmaf(pv.z, af.z, gf); gf = fmaf(pv.w, af.w, gf);
        gg = fmaf(pv.x, ag.x, gg); gg = fmaf(pv.y, ag.y, gg);
        gg = fmaf(pv.z, ag.z, gg); gg = fmaf(pv.w, ag.w, gg);
      }
#pragma unroll
      for (int b4 = 0; b4 < BSZ; b4 += 4) {
        const float4 pv = *(const float4*)&PL[ob][BSZ + b4];
        const float4 ai = *(const float4*)&ars[ohc][b4];
        const float4 af = *(const float4*)&ars[4 + ohc][b4];
        const float4 ag = *(const float4*)&ars[8 + ohc][b4];
        gi = fmaf(pv.x, ai.x, gi); gi = fmaf(pv.y, ai.y, gi);
        gi = fmaf(pv.z, ai.z, gi); gi = fmaf(pv.w, ai.w, gi);
        gf = fmaf(pv.x, af.x, gf); gf = fmaf(pv.y, af.y, gf);
        gf = fmaf(pv.z, af.z, gf); gf = fmaf(pv.w, af.w, gf);
        gg = fmaf(pv.x, ag.x, gg); gg = fmaf(pv.y, ag.y, gg);
        gg = fmaf(pv.z, ag.z, gg); gg = fmaf(pv.w, ag.w, gg);
      }
      const float iv = 1.f / (1.f + expf(-gi));
      const float fv = 1.f / (1.f + expf(-gf));
      const float gv = tanhf(gg);
      creg = fmaf(fv, creg, iv * gv);
      hpub[tid] = iv * tanhf(creg);  // o_t = i_t (faithful to source)
    }
    __syncthreads();  // F: hpub complete

    // ---- wave 0: publish 512B (64 lanes x dwordx2) + counter -------------
    if (tid < 64) {
      const float2 val = *(const float2*)&hpub[tid * 2];
      const uint64_t daddr =
          (uint64_t)(hbank + (size_t)(t + 1) * HSLICE + (size_t)wg * (BSZ * HS)) +
          (uint64_t)tid * 8u;
      asm volatile(
          "global_store_dwordx2 %0, %1, off sc0 sc1\n\t"
          "s_waitcnt vmcnt(0)"
          :: "v"(daddr), "v"(val)
          : "memory");
      if (tid == 0) {
        __hip_atomic_fetch_add(cnt, 1u, __ATOMIC_RELAXED,
                               __HIP_MEMORY_SCOPE_AGENT);
      }
    }
  }
}

// ------------------------------ Output -------------------------------------
__global__ void outK(const float* __restrict__ hbank, const float* __restrict__ W_out,
                     const float* __restrict__ b_out, float* __restrict__ out) {
  const int b = threadIdx.x;
  if (b < BSZ) {
    const float* h = hbank + (size_t)T_STEPS * HSLICE;  // [wg][b][c]
    float s = 0.f;
    for (int wg = 0; wg < KWG; ++wg) {
      const float4 hv = *(const float4*)&h[wg * (BSZ * HS) + b * HS];
      const float4 wv = *(const float4*)&W_out[wg * HS];
      s = fmaf(hv.x, wv.x, s); s = fmaf(hv.y, wv.y, s);
      s = fmaf(hv.z, wv.z, s); s = fmaf(hv.w, wv.w, s);
    }
    out[b] = s + b_out[0];
  }
}

// ------------------------------ Launch -------------------------------------
extern "C" void kernel_launch(void* const* d_in, const int* in_sizes, int n_in,
                              void* d_out, int out_size, void* d_ws, size_t ws_size,
                              hipStream_t stream) {
  const float* x      = (const float*)d_in[0];
  const float* W      = (const float*)d_in[1];
  const float* U      = (const float*)d_in[2];
  const float* P      = (const float*)d_in[3];
  const float* B_bias = (const float*)d_in[4];
  const float* W_r    = (const float*)d_in[5];
  const float* P_r    = (const float*)d_in[6];
  const float* U_r    = (const float*)d_in[7];
  const float* W_out  = (const float*)d_in[8];
  const float* b_out  = (const float*)d_in[9];

  char* ws = (char*)d_ws;
  float*    AXc   = (float*)ws;
  float*    hbank = (float*)(ws + AXC_BYTES);
  double*   gx    = (double*)(ws + AXC_BYTES + HB_BYTES);
  unsigned* cnt   = (unsigned*)(ws + AXC_BYTES + HB_BYTES + GX_BYTES);

  hipMemsetAsync(hbank, 0, (size_t)HSLICE * sizeof(float), stream);  // h0 = 0
  hipMemsetAsync(cnt, 0, 256, stream);                               // counter

  phaseA<<<T_STEPS, 256, 0, stream>>>(x, W, W_r, P_r, AXc, gx);
  phaseB<<<KWG, 256, 0, stream>>>(U, P, B_bias, P_r, U_r, AXc, hbank, gx, cnt);
  outK<<<1, 64, 0, stream>>>(hbank, W_out, b_out, (float*)d_out);
}